// Round 3
// baseline (391.088 us; speedup 1.0000x reference)
//
#include <hip/hip_runtime.h>
#include <cfloat>
#include <cstdint>

#define NN 8192      // nodes
#define DD 128       // features
#define TOPK 32

// monotonic float -> uint mapping (descending float == descending uint)
__device__ __forceinline__ uint32_t f2s(float f) {
  uint32_t u = __float_as_uint(f);
  return (u & 0x80000000u) ? ~u : (u | 0x80000000u);
}
__device__ __forceinline__ float s2f(uint32_t s) {
  return (s & 0x80000000u) ? __uint_as_float(s & 0x7fffffffu)
                           : __uint_as_float(~s);
}

// Exact top-32 (value,index) per feature column, descending, packed float2.
// One block per feature d.
__global__ __launch_bounds__(256) void topk_kernel(
    const float* __restrict__ x, float2* __restrict__ tk) {
  const int d = blockIdx.x;
  const int t = threadIdx.x;
  const int lane = t & 63;
  const int wv = t >> 6;

  __shared__ unsigned long long red[4];
  __shared__ unsigned long long bcast;

  unsigned long long key[32];
#pragma unroll
  for (int e = 0; e < 32; ++e) {
    int j = t * 32 + e;
    key[e] = ((unsigned long long)f2s(x[(size_t)j * DD + d]) << 32) | (unsigned)j;
  }
  unsigned long long prev = ~0ull;  // keys strictly below prev each round
  for (int k = 0; k < TOPK; ++k) {
    unsigned long long best = 0ull;
#pragma unroll
    for (int e = 0; e < 32; ++e)
      if (key[e] < prev && key[e] > best) best = key[e];
    for (int off = 32; off; off >>= 1) {
      unsigned long long o = __shfl_down(best, off, 64);
      if (o > best) best = o;
    }
    if (lane == 0) red[wv] = best;
    __syncthreads();
    if (t == 0) {
      unsigned long long m = red[0];
      for (int i = 1; i < 4; ++i) if (red[i] > m) m = red[i];
      bcast = m;
      float2 kv;
      kv.x = s2f((uint32_t)(m >> 32));
      kv.y = __int_as_float((int)(uint32_t)(m & 0xffffffffu));
      tk[k * DD + d] = kv;
    }
    __syncthreads();
    prev = bcast;
  }
}

// Direct-probe kernel: 2 rows per block; wave = 64 features of one row.
// Probes adj[row, tki[k,d]] directly (predicated — finished lanes issue no
// loads). Expected ~2 probes per (row,d). Fallback full-row scan covers both
// "neighbors exist but none in top-32" (P ~ 2^-32) and "no neighbors" (-> 0).
__global__ __launch_bounds__(256) void probe_kernel(
    const float* __restrict__ x, const int* __restrict__ adj,
    const float2* __restrict__ tk, float* __restrict__ out) {
  const int t = threadIdx.x;
  const int row = blockIdx.x * 2 + (t >> 7);
  const int d = t & 127;
  const int* __restrict__ arow = adj + (size_t)row * NN;

  float res = 0.0f;
  bool done = false;
  for (int k = 0; k < TOPK; ++k) {
    if (!done) {
      float2 kv = tk[k * DD + d];
      int idx = __float_as_int(kv.y);
      if (arow[idx] != 0) { res = kv.x; done = true; }
    }
    if (__all((int)done)) break;  // wave-uniform early exit
  }
  if (__any((int)(!done))) {
    // rare path: wave-uniform adj scan (scalar broadcast), coalesced x loads
    if (!done) {
      float m = -FLT_MAX;
      bool any = false;
      for (int j = 0; j < NN; ++j) {
        if (arow[j] != 0) { any = true; m = fmaxf(m, x[(size_t)j * DD + d]); }
      }
      res = any ? m : 0.0f;
    }
  }
  out[(size_t)row * DD + d] = res;
}

extern "C" void kernel_launch(void* const* d_in, const int* in_sizes, int n_in,
                              void* d_out, int out_size, void* d_ws, size_t ws_size,
                              hipStream_t stream) {
  const float* x = (const float*)d_in[0];   // [8192,128] f32
  const int* adj = (const int*)d_in[1];     // [8192,8192] i32
  float* out = (float*)d_out;               // [8192,128] f32

  float2* tk = (float2*)d_ws;               // 32 KB: top-32 (val, idx-as-float) per feature

  topk_kernel<<<DD, 256, 0, stream>>>(x, tk);
  probe_kernel<<<NN / 2, 256, 0, stream>>>(x, adj, tk, out);
}